// Round 1
// baseline (435.397 us; speedup 1.0000x reference)
//
#include <hip/hip_runtime.h>
#include <math.h>

#define B_DIM 16384
#define D_DIM 64
#define H_DIM 1024
#define CLAMP_V 10.0f

// ---------------------------------------------------------------------------
// Prep: build masked weights in workspace (ws is re-poisoned every call, so
// this runs every launch — ~768 KB of writes, negligible).
//   W1mT[i*H + h] = W1[h*D + i] * (i <= h%63)        (D x H, transposed)
//   W2m [j*H + h] = W2[j*H + h] * ((h%63) < (j>>1))  (2D x H, row-major)
// ---------------------------------------------------------------------------
__global__ void maf_prep_kernel(const float* __restrict__ W1,
                                const float* __restrict__ W2,
                                float* __restrict__ W1mT,
                                float* __restrict__ W2m) {
    int idx = blockIdx.x * blockDim.x + threadIdx.x;
    if (idx < D_DIM * H_DIM) {
        int i = idx >> 10;            // / H_DIM
        int h = idx & (H_DIM - 1);
        int m0 = h % (D_DIM - 1);
        float v = W1[h * D_DIM + i];
        W1mT[idx] = (i <= m0) ? v : 0.0f;
    } else {
        int idx2 = idx - D_DIM * H_DIM;
        if (idx2 < 2 * D_DIM * H_DIM) {
            int j = idx2 >> 10;
            int h = idx2 & (H_DIM - 1);
            int m0 = h % (D_DIM - 1);
            float v = W2[idx2];
            W2m[idx2] = (m0 < (j >> 1)) ? v : 0.0f;
        }
    }
}

__device__ __forceinline__ float fast_tanh(float x) {
    // tanh(x) = 1 - 2/(exp(2x)+1); saturates correctly at +/-inf.
    float e = __expf(2.0f * x);
    float r = __builtin_amdgcn_rcpf(e + 1.0f);
    return fmaf(-2.0f, r, 1.0f);
}

__device__ __forceinline__ float clampv(float v) {
    return fminf(fmaxf(v, -CLAMP_V), CLAMP_V);
}

// ---------------------------------------------------------------------------
// Main: one wave (64 lanes) per batch element; 4 waves per block.
// Lane owns s[h] for h = 256*k + 4*lane + j  (k in 0..3, j in 0..3)
// Per step i:
//   t = tanh(s); mu_i = <t, W2m[i,:]>; al_i = <t, W2m[D+i,:]>  (butterfly sum)
//   x_i = z_i * exp(al) + mu;  ld += al;  s += x_i * W1mT[i,:]
// ---------------------------------------------------------------------------
__global__ __launch_bounds__(256) void maf_main_kernel(
    const float* __restrict__ z,  const float* __restrict__ b1,
    const float* __restrict__ b2, const float* __restrict__ W1mT,
    const float* __restrict__ W2m, float* __restrict__ out) {
    const int wave = threadIdx.x >> 6;
    const int lane = threadIdx.x & 63;
    const int b = blockIdx.x * 4 + wave;
    const int hbase = lane * 4;      // float offset within a 256-float chunk

    // init s = b1 (coalesced float4 loads)
    float4 s[4];
#pragma unroll
    for (int k = 0; k < 4; k++)
        s[k] = *reinterpret_cast<const float4*>(&b1[256 * k + hbase]);

    const float zreg = z[b * D_DIM + lane];   // z row, one element per lane
    float ld = 0.0f;
    float xrow = 0.0f;

#pragma unroll 1
    for (int i = 0; i < D_DIM; i++) {
        const float4* w2mu = reinterpret_cast<const float4*>(&W2m[i * H_DIM + hbase]);
        const float4* w2al = reinterpret_cast<const float4*>(&W2m[(D_DIM + i) * H_DIM + hbase]);
        float dm = 0.0f, da = 0.0f;
#pragma unroll
        for (int k = 0; k < 4; k++) {
            float4 m4 = w2mu[k * 64];   // float offset 256*k
            float4 a4 = w2al[k * 64];
            float4 sv = s[k];
            float t0 = fast_tanh(sv.x);
            float t1 = fast_tanh(sv.y);
            float t2 = fast_tanh(sv.z);
            float t3 = fast_tanh(sv.w);
            dm = fmaf(t0, m4.x, fmaf(t1, m4.y, fmaf(t2, m4.z, fmaf(t3, m4.w, dm))));
            da = fmaf(t0, a4.x, fmaf(t1, a4.y, fmaf(t2, a4.z, fmaf(t3, a4.w, da))));
        }
        // 64-lane butterfly: every lane ends with the full sums
#pragma unroll
        for (int off = 32; off > 0; off >>= 1) {
            dm += __shfl_xor(dm, off);
            da += __shfl_xor(da, off);
        }
        float mu = clampv(dm + b2[i]);
        float al = clampv(da + b2[D_DIM + i]);
        float zi = __shfl(zreg, i);
        float xi = fmaf(zi, __expf(al), mu);
        ld += al;
        if (lane == i) xrow = xi;

        const float4* w1c = reinterpret_cast<const float4*>(&W1mT[i * H_DIM + hbase]);
#pragma unroll
        for (int k = 0; k < 4; k++) {
            float4 w = w1c[k * 64];
            s[k].x = fmaf(xi, w.x, s[k].x);
            s[k].y = fmaf(xi, w.y, s[k].y);
            s[k].z = fmaf(xi, w.z, s[k].z);
            s[k].w = fmaf(xi, w.w, s[k].w);
        }
    }

    if (!isfinite(xrow)) xrow = 0.0f;
    out[b * D_DIM + lane] = xrow;
    if (lane == 0) {
        if (!isfinite(ld)) ld = 0.0f;
        out[B_DIM * D_DIM + b] = ld;
    }
}

extern "C" void kernel_launch(void* const* d_in, const int* in_sizes, int n_in,
                              void* d_out, int out_size, void* d_ws, size_t ws_size,
                              hipStream_t stream) {
    const float* z  = (const float*)d_in[0];   // (B, D)
    const float* W1 = (const float*)d_in[1];   // (H, D)
    const float* b1 = (const float*)d_in[2];   // (H,)
    const float* W2 = (const float*)d_in[3];   // (2D, H)
    const float* b2 = (const float*)d_in[4];   // (2D,)
    float* out = (float*)d_out;                // x (B*D) then log_det (B)

    float* W1mT = (float*)d_ws;                // D*H floats
    float* W2m  = W1mT + D_DIM * H_DIM;        // 2D*H floats (total 768 KB)

    const int prep_elems = D_DIM * H_DIM + 2 * D_DIM * H_DIM;  // 196608
    maf_prep_kernel<<<(prep_elems + 255) / 256, 256, 0, stream>>>(W1, W2, W1mT, W2m);

    maf_main_kernel<<<B_DIM / 4, 256, 0, stream>>>(z, b1, b2, W1mT, W2m, out);
}